// Round 1
// baseline (256.421 us; speedup 1.0000x reference)
//
#include <hip/hip_runtime.h>

#define NCONDS 50
#define EMB 64
#define ROW_STRIDE (1 + NCONDS)          // 51 indices per row
#define OUT_STRIDE ((1 + NCONDS) * EMB)  // 3264 floats per row

// One wave (64 lanes) per batch row.
// Lanes split into 4 groups of 16; each lane holds float4 (4 dims of 64).
// Each group handles one condition per iteration -> 4 conditions / iter.
__global__ __launch_bounds__(256) void cond_filter_kernel(
    const int*   __restrict__ inp,     // (B, 51) int32
    const float* __restrict__ table,   // (100002, 64) fp32
    float*       __restrict__ out,     // (B, 3264) fp32
    int batch)
{
    const int wave = threadIdx.x >> 6;            // 0..3
    const int lane = threadIdx.x & 63;
    const int b = blockIdx.x * 4 + wave;
    if (b >= batch) return;

    const int grp = lane >> 4;                    // condition group 0..3
    const int gl  = lane & 15;                    // lane within group

    const int* row = inp + (size_t)b * ROW_STRIDE;
    const int e_idx = row[0];

    // Event embedding: 16 lanes x float4 = 64 dims (replicated in all 4 groups)
    const float4 ev = *(const float4*)(table + (size_t)e_idx * EMB + gl * 4);

    // sum of squares, reduced across the 16-lane group (xor masks 1,2,4,8)
    float es = ev.x*ev.x + ev.y*ev.y + ev.z*ev.z + ev.w*ev.w;
    #pragma unroll
    for (int m = 1; m < 16; m <<= 1) es += __shfl_xor(es, m, 64);
    const float e_rn = rsqrtf(es);
    const float4 en = make_float4(ev.x*e_rn, ev.y*e_rn, ev.z*e_rn, ev.w*e_rn);

    float* orow = out + (size_t)b * OUT_STRIDE;
    if (grp == 0) {
        // raw (un-normalized) event embedding, per reference
        *(float4*)(orow + gl * 4) = ev;
    }

    #pragma unroll 1
    for (int base = 0; base < NCONDS; base += 4) {
        const int c = base + grp;
        const bool active = (c < NCONDS);
        const int ci = active ? row[1 + c] : e_idx;  // safe dummy for tail

        const float4 cv = *(const float4*)(table + (size_t)ci * EMB + gl * 4);

        float cs = cv.x*cv.x + cv.y*cv.y + cv.z*cv.z + cv.w*cv.w;
        float dp = cv.x*en.x + cv.y*en.y + cv.z*en.z + cv.w*en.w;
        #pragma unroll
        for (int m = 1; m < 16; m <<= 1) {
            cs += __shfl_xor(cs, m, 64);
            dp += __shfl_xor(dp, m, 64);
        }

        // filtered = (cv/|cv|) * dot(e_nrm, cv/|cv|) = cv * dp / cs
        const float scale = dp / cs;

        if (active) {
            float4 o = make_float4(cv.x*scale, cv.y*scale, cv.z*scale, cv.w*scale);
            *(float4*)(orow + EMB + (size_t)c * EMB + gl * 4) = o;
        }
    }
}

extern "C" void kernel_launch(void* const* d_in, const int* in_sizes, int n_in,
                              void* d_out, int out_size, void* d_ws, size_t ws_size,
                              hipStream_t stream) {
    const int*   inp   = (const int*)d_in[0];
    const float* table = (const float*)d_in[1];
    float*       out   = (float*)d_out;

    const int batch = in_sizes[0] / ROW_STRIDE;   // 16384
    const int blocks = (batch + 3) / 4;           // 4 rows per 256-thread block

    hipLaunchKernelGGL(cond_filter_kernel, dim3(blocks), dim3(256), 0, stream,
                       inp, table, out, batch);
}

// Round 2
// 250.054 us; speedup vs baseline: 1.0255x; 1.0255x over previous
//
#include <hip/hip_runtime.h>

#define NCONDS 50
#define EMB 64
#define ROW_STRIDE (1 + NCONDS)          // 51 indices per row
#define OUT_STRIDE ((1 + NCONDS) * EMB)  // 3264 floats per row
#define NITER 13                         // ceil(50/4) condition iterations

typedef float f4 __attribute__((ext_vector_type(4)));

// One wave (64 lanes) per batch row.
// Lanes split into 4 groups of 16; each lane holds f4 (4 dims of 64).
// All 13 gathers issued up-front (full unroll) for max memory-level parallelism.
__global__ __launch_bounds__(256) void cond_filter_kernel(
    const int*   __restrict__ inp,     // (B, 51) int32
    const float* __restrict__ table,   // (100002, 64) fp32
    float*       __restrict__ out,     // (B, 3264) fp32
    int batch)
{
    const int wave = threadIdx.x >> 6;            // 0..3
    const int lane = threadIdx.x & 63;
    const int b = blockIdx.x * 4 + wave;
    if (b >= batch) return;

    const int grp = lane >> 4;                    // condition group 0..3
    const int gl  = lane & 15;                    // lane within group

    // Coalesced one-shot load of all 51 indices; broadcast via register shfl.
    const int* row = inp + (size_t)b * ROW_STRIDE;
    const int my_idx = (lane < ROW_STRIDE) ? row[lane] : 0;
    const int e_idx = __shfl(my_idx, 0, 64);

    // Condition index for this group's slot in each iteration (register-only).
    int cidx[NITER];
    #pragma unroll
    for (int i = 0; i < NITER; ++i) {
        const int c = i * 4 + grp;
        const int src = (c < NCONDS) ? (1 + c) : 0;   // tail -> dummy (event idx)
        cidx[i] = __shfl(my_idx, src, 64);
    }

    // Issue event gather + all 13 condition gathers back-to-back (13+1 in flight).
    const f4 ev = *(const f4*)(table + (size_t)e_idx * EMB + gl * 4);
    f4 cv[NITER];
    #pragma unroll
    for (int i = 0; i < NITER; ++i)
        cv[i] = *(const f4*)(table + (size_t)cidx[i] * EMB + gl * 4);

    // Event norm (16-lane group reduction; replicated across the 4 groups).
    float es = ev.x*ev.x + ev.y*ev.y + ev.z*ev.z + ev.w*ev.w;
    #pragma unroll
    for (int m = 1; m < 16; m <<= 1) es += __shfl_xor(es, m, 64);
    const float e_rn = rsqrtf(es);
    const f4 en = ev * e_rn;

    float* orow = out + (size_t)b * OUT_STRIDE;
    if (grp == 0) {
        // raw (un-normalized) event embedding, per reference; write-once -> nt
        __builtin_nontemporal_store(ev, (f4*)(orow + gl * 4));
    }

    // 13 independent reduce chains; compiler interleaves shfl latency across them.
    #pragma unroll
    for (int i = 0; i < NITER; ++i) {
        const int c = i * 4 + grp;
        const f4 v = cv[i];
        float cs = v.x*v.x + v.y*v.y + v.z*v.z + v.w*v.w;
        float dp = v.x*en.x + v.y*en.y + v.z*en.z + v.w*en.w;
        #pragma unroll
        for (int m = 1; m < 16; m <<= 1) {
            cs += __shfl_xor(cs, m, 64);
            dp += __shfl_xor(dp, m, 64);
        }
        // filtered = (v/|v|) * dot(en, v/|v|) = v * dp / cs
        const float scale = dp * __builtin_amdgcn_rcpf(cs);
        if (c < NCONDS) {
            const f4 o = v * scale;
            __builtin_nontemporal_store(o, (f4*)(orow + EMB + (size_t)c * EMB + gl * 4));
        }
    }
}

extern "C" void kernel_launch(void* const* d_in, const int* in_sizes, int n_in,
                              void* d_out, int out_size, void* d_ws, size_t ws_size,
                              hipStream_t stream) {
    const int*   inp   = (const int*)d_in[0];
    const float* table = (const float*)d_in[1];
    float*       out   = (float*)d_out;

    const int batch = in_sizes[0] / ROW_STRIDE;   // 16384
    const int blocks = (batch + 3) / 4;           // 4 rows per 256-thread block

    hipLaunchKernelGGL(cond_filter_kernel, dim3(blocks), dim3(256), 0, stream,
                       inp, table, out, batch);
}

// Round 3
// 249.077 us; speedup vs baseline: 1.0295x; 1.0039x over previous
//
#include <hip/hip_runtime.h>

#define NCONDS 50
#define EMB 64
#define ROW_STRIDE (1 + NCONDS)          // 51 indices per row
#define OUT_STRIDE ((1 + NCONDS) * EMB)  // 3264 floats per row
#define NITER 13                         // ceil(50/4) condition iterations

typedef float f4 __attribute__((ext_vector_type(4)));

// 16-lane-row sum reduction on the VALU via DPP row_ror (no DS pipe, no lgkmcnt).
// row_ror:N -> dpp_ctrl 0x120|N. All 64 lanes are active at every reduce site.
template<int CTRL>
__device__ __forceinline__ float dpp_add(float x) {
    int y = __builtin_amdgcn_update_dpp(0, __builtin_bit_cast(int, x),
                                        CTRL, 0xf, 0xf, true);
    return x + __builtin_bit_cast(float, y);
}
__device__ __forceinline__ float reduce16(float x) {
    x = dpp_add<0x121>(x);   // ror 1
    x = dpp_add<0x122>(x);   // ror 2
    x = dpp_add<0x124>(x);   // ror 4
    x = dpp_add<0x128>(x);   // ror 8
    return x;                // every lane holds the 16-lane sum
}

// One wave per batch row; 4 groups of 16 lanes; lane holds f4 (4 of 64 dims).
// Indices via scalar loads (wave-uniform row), reductions via DPP -> zero DS ops.
__global__ __launch_bounds__(256) void cond_filter_kernel(
    const int*   __restrict__ inp,     // (B, 51) int32
    const float* __restrict__ table,   // (100002, 64) fp32
    float*       __restrict__ out,     // (B, 3264) fp32
    int batch)
{
    const int wave = threadIdx.x >> 6;            // 0..3
    const int lane = threadIdx.x & 63;
    int b = blockIdx.x * 4 + wave;
    b = __builtin_amdgcn_readfirstlane(b);        // prove wave-uniform -> s_loads
    if (b >= batch) return;

    const int grp = lane >> 4;                    // condition group 0..3
    const int gl  = lane & 15;                    // lane within group

    const int* row = inp + (size_t)b * ROW_STRIDE;
    const int e_idx = row[0];                     // scalar load

    // Per-iteration condition index: 4 scalar loads + 2-level cndmask select.
    int cidx[NITER];
    #pragma unroll
    for (int i = 0; i < NITER; ++i) {
        const int base = 1 + i * 4;
        const int s0 = row[base];
        const int s1 = (base + 1 < ROW_STRIDE) ? row[base + 1] : s0;
        const int s2 = (base + 2 < ROW_STRIDE) ? row[base + 2] : s0;
        const int s3 = (base + 3 < ROW_STRIDE) ? row[base + 3] : s0;
        cidx[i] = (grp & 1) ? ((grp & 2) ? s3 : s1)
                            : ((grp & 2) ? s2 : s0);
    }

    // Issue event gather + all 13 condition gathers back-to-back (max MLP).
    const f4 ev = *(const f4*)(table + (size_t)e_idx * EMB + gl * 4);
    f4 cv[NITER];
    #pragma unroll
    for (int i = 0; i < NITER; ++i)
        cv[i] = *(const f4*)(table + (size_t)cidx[i] * EMB + gl * 4);

    // Event norm (replicated across the 4 groups).
    const float es = reduce16(ev.x*ev.x + ev.y*ev.y + ev.z*ev.z + ev.w*ev.w);
    const float e_rn = rsqrtf(es);
    const f4 en = ev * e_rn;

    float* orow = out + (size_t)b * OUT_STRIDE;
    if (grp == 0) {
        // raw (un-normalized) event embedding, per reference; write-once -> nt
        __builtin_nontemporal_store(ev, (f4*)(orow + gl * 4));
    }

    #pragma unroll
    for (int i = 0; i < NITER; ++i) {
        const int c = i * 4 + grp;
        const f4 v = cv[i];
        const float cs = reduce16(v.x*v.x + v.y*v.y + v.z*v.z + v.w*v.w);
        const float dp = reduce16(v.x*en.x + v.y*en.y + v.z*en.z + v.w*en.w);
        // filtered = (v/|v|) * dot(en, v/|v|) = v * dp / cs
        const float scale = dp * __builtin_amdgcn_rcpf(cs);
        if (c < NCONDS) {
            const f4 o = v * scale;
            __builtin_nontemporal_store(o, (f4*)(orow + EMB + (size_t)c * EMB + gl * 4));
        }
    }
}

extern "C" void kernel_launch(void* const* d_in, const int* in_sizes, int n_in,
                              void* d_out, int out_size, void* d_ws, size_t ws_size,
                              hipStream_t stream) {
    const int*   inp   = (const int*)d_in[0];
    const float* table = (const float*)d_in[1];
    float*       out   = (float*)d_out;

    const int batch = in_sizes[0] / ROW_STRIDE;   // 16384
    const int blocks = (batch + 3) / 4;           // 4 rows per 256-thread block

    hipLaunchKernelGGL(cond_filter_kernel, dim3(blocks), dim3(256), 0, stream,
                       inp, table, out, batch);
}